// Round 8
// baseline (364.321 us; speedup 1.0000x reference)
//
#include <hip/hip_runtime.h>

typedef __attribute__((ext_vector_type(8))) short short8;
typedef __attribute__((ext_vector_type(16))) float f32x16;
typedef unsigned short ushort_t;

#define BAR()   __builtin_amdgcn_s_barrier()
#define LGKM0() asm volatile("s_waitcnt lgkmcnt(0)" ::: "memory")
#define VM6()   asm volatile("s_waitcnt vmcnt(6)" ::: "memory")
#define VM0()   asm volatile("s_waitcnt vmcnt(0)" ::: "memory")
#define PRIO(n) __builtin_amdgcn_s_setprio(n)
#define MFMA32(a_, b_, c_) __builtin_amdgcn_mfma_f32_32x32x16_bf16(a_, b_, c_, 0, 0, 0)

// ---------- helpers ----------
__device__ __forceinline__ unsigned short f2bf(float f) {
  unsigned u = __builtin_bit_cast(unsigned, f);
  u += 0x7FFFu + ((u >> 16) & 1u);   // round-to-nearest-even
  return (unsigned short)(u >> 16);
}

__device__ __forceinline__ void gl_lds16(const void* g, void* l) {
  __builtin_amdgcn_global_load_lds(
      (const __attribute__((address_space(1))) void*)g,
      (__attribute__((address_space(3))) void*)l, 16, 0, 0);
}

// ---------- kernel 1: x (f32) -> bf16 ----------
__global__ __launch_bounds__(256) void cvt_x(const float* __restrict__ x,
                                             ushort_t* __restrict__ xb) {
  size_t i = ((size_t)blockIdx.x * 256 + threadIdx.x) * 8;
  float4 v0 = *(const float4*)(x + i);
  float4 v1 = *(const float4*)(x + i + 4);
  union { ushort_t s[8]; uint4 v; } o;
  o.s[0] = f2bf(v0.x); o.s[1] = f2bf(v0.y); o.s[2] = f2bf(v0.z); o.s[3] = f2bf(v0.w);
  o.s[4] = f2bf(v1.x); o.s[5] = f2bf(v1.y); o.s[6] = f2bf(v1.z); o.s[7] = f2bf(v1.w);
  *(uint4*)(xb + i) = o.v;
}

// ---------- kernel 2: W_eff = W + A@B, stored bf16 ----------
__global__ __launch_bounds__(256) void build_weff(const float* __restrict__ W,
                                                  const float* __restrict__ A,
                                                  const float* __restrict__ B,
                                                  ushort_t* __restrict__ Weff) {
  const int K = 4096, R = 16;
  const int n = blockIdx.y;
  const int k = (blockIdx.x * 256 + threadIdx.x) * 4;
  float4 w = *(const float4*)(W + (size_t)n * K + k);
  float a0 = w.x, a1 = w.y, a2 = w.z, a3 = w.w;
#pragma unroll
  for (int r = 0; r < R; ++r) {
    float a = A[n * R + r];
    float4 b = *(const float4*)(B + (size_t)r * K + k);
    a0 += a * b.x; a1 += a * b.y; a2 += a * b.z; a3 += a * b.w;
  }
  union { ushort_t s[4]; uint2 v; } o;
  o.s[0] = f2bf(a0); o.s[1] = f2bf(a1); o.s[2] = f2bf(a2); o.s[3] = f2bf(a3);
  *(uint2*)(Weff + (size_t)n * K + k) = o.v;
}

// ---------- kernel 3: 256x256 8-phase bf16 GEMM, 32x32x16 MFMA ----------
// EXACT round-4 base (250 us, bank-conflict==0 measured): LDS [2][4][256r][32c],
// k-half tiles, phase/stage/vmcnt schedule identical. ONLY the MFMA shape and
// fragment mapping change: 16x16x32 (64/tile/wave) -> 32x32x16 (32/tile/wave).
//   Per-wave C = 128x64 = 4 m-frags x 2 n-frags of 32x32, acc f32x16 each.
//   A/B frag (m74/m101 family): lane holds row/col = l&31, k = (l>>5)*8 + j.
//   C/D frag: col = l&31, row = (reg&3) + 8*(reg>>2) + 4*(l>>5).
// Reads: 24 b128/wave/tile (A: 4mi x 2ks x 2kh = 16, B: 2ni x 2ks x 2kh = 8).
// Bank pattern of reads: quad bits {(l>>5)&1, ks^((l>>3)&1), l&1} -> 4 lanes
// per bank-quad within each quarter-wave == round-4's measured-zero pattern.
// Swizzle: byte col = ((l>>5)*16) ^ ((l>>3)&1)<<5; ks-slice = XOR bit 5 (32B).
// Stage side byte-identical to round 4 (pre-swizzled global src, linear dest).
// Phases per K-tile:
//   P1: rd a0-1 (4) + b0-1 (4) of kh0; stage A-k1(t+1)->cur^1; 8 MFMA m0-1
//   P2: rd a2-3 kh0 (4);              stage B-k0(t+2)->cur;    8 MFMA m2-3
//   P3: rd a0-1 + b kh1 (8);          stage A-k0(t+2)->cur;    8 MFMA m0-1
//   P4: rd a2-3 kh1 (4);              stage B-k1(t+2)->cur; vmcnt(6); 8 MFMA
// WAR + vmcnt ledgers identical to round 4 (verified there).

__device__ __forceinline__ void stage_half(const ushort_t* __restrict__ G, int row0, int kc,
                                           ushort_t* half, int tid) {
#pragma unroll
  for (int r = 0; r < 2; ++r) {
    const int idx  = r * 512 + tid;
    const int lrow = idx >> 2;                                    // 0..255
    const int cb   = ((idx & 3) * 16) ^ (((lrow >> 3) & 1) << 5); // pre-swizzled source col (bytes)
    const ushort_t* src = G + (size_t)(row0 + lrow) * 4096 + kc + (cb >> 1);
    char* dst = (char*)half + (size_t)(r * 512 + (tid & ~63)) * 16; // wave-uniform; HW adds lane*16
    gl_lds16(src, dst);
  }
}

__global__ __launch_bounds__(512) void gemm256(const ushort_t* __restrict__ Xb,
                                               const ushort_t* __restrict__ Wb,
                                               float* __restrict__ C) {
  const int N = 4096;
  const int NT = 4096 / 64;                 // 64 K-tiles
  __shared__ __align__(16) ushort_t lds[2][4][256 * 32];  // [buf][A-k0,A-k1,B-k0,B-k1]

  const int tid = threadIdx.x;
  const int l   = tid & 63;
  const int w   = tid >> 6;
  const int wm  = w >> 2;                   // 0..1
  const int wn  = w & 3;                    // 0..3

  // T1: bijective XCD chunking — 512 blocks = 8 chunks of 8x8 tiles (grid 32x16)
  const int bid = blockIdx.x;
  const int c = bid & 7, q = bid >> 3;
  const int tm = (c >> 1) * 8 + (q >> 3);   // 0..31
  const int tn = (c & 1) * 8 + (q & 7);     // 0..15
  const int bm = tm * 256, bn = tn * 256;

  // fragment byte offsets within a [256][32] half (swizzled read side).
  // row stride 64 B; lane row = l&31; k-chunk byte = (l>>5)*16; ks slice = ^32.
  const int colb0 = ((l >> 5) * 16) ^ (((l >> 3) & 1) << 5);
  int aoff[4], boff[2];
#pragma unroll
  for (int mi = 0; mi < 4; ++mi) aoff[mi] = (wm * 128 + mi * 32 + (l & 31)) * 64 + colb0;
#pragma unroll
  for (int ni = 0; ni < 2; ++ni) boff[ni] = (wn * 64 + ni * 32 + (l & 31)) * 64 + colb0;

  f32x16 acc[4][2];
#pragma unroll
  for (int i = 0; i < 4; ++i)
#pragma unroll
    for (int j = 0; j < 2; ++j) acc[i][j] = (f32x16)(0.0f);

  // prologue: tile0 all 4 halves + tile1 {B-k0,A-k0,B-k1}; vmcnt(6) -> tile0 landed
  stage_half(Wb, bn, 0,  lds[0][2], tid);
  stage_half(Xb, bm, 0,  lds[0][0], tid);
  stage_half(Wb, bn, 32, lds[0][3], tid);
  stage_half(Xb, bm, 32, lds[0][1], tid);
  stage_half(Wb, bn, 64, lds[1][2], tid);
  stage_half(Xb, bm, 64, lds[1][0], tid);
  stage_half(Wb, bn, 96, lds[1][3], tid);
  VM6();
  BAR();

  short8 a01[2][2], a23[2][2], bb[2][2];   // [m-or-n idx][ks]

#define RD(P_) (*(const short8*)(P_))

  int cur = 0;
  for (int t = 0; t < NT; ++t) {
    const char* A0h = (const char*)lds[cur][0];
    const char* A1h = (const char*)lds[cur][1];
    const char* B0h = (const char*)lds[cur][2];
    const char* B1h = (const char*)lds[cur][3];
    const int kc2 = (t + 2) * 64;

    // ---- P1: rd a0-1 + b0-1 (kh0); stage A-k1(t+1); 8 MFMA m0-1 ----
#pragma unroll
    for (int mi = 0; mi < 2; ++mi)
#pragma unroll
      for (int ks = 0; ks < 2; ++ks) a01[mi][ks] = RD(A0h + (aoff[mi] ^ (ks << 5)));
#pragma unroll
    for (int ni = 0; ni < 2; ++ni)
#pragma unroll
      for (int ks = 0; ks < 2; ++ks) bb[ni][ks] = RD(B0h + (boff[ni] ^ (ks << 5)));
    if (t + 1 < NT) stage_half(Xb, bm, (t + 1) * 64 + 32, lds[cur ^ 1][1], tid);
    BAR(); LGKM0(); PRIO(1);
#pragma unroll
    for (int ks = 0; ks < 2; ++ks)
#pragma unroll
      for (int mi = 0; mi < 2; ++mi)
#pragma unroll
        for (int ni = 0; ni < 2; ++ni)
          acc[mi][ni] = MFMA32(a01[mi][ks], bb[ni][ks], acc[mi][ni]);
    PRIO(0); BAR();

    // ---- P2: rd a2-3 (kh0); stage B-k0(t+2); 8 MFMA m2-3 ----
#pragma unroll
    for (int mi = 0; mi < 2; ++mi)
#pragma unroll
      for (int ks = 0; ks < 2; ++ks) a23[mi][ks] = RD(A0h + (aoff[2 + mi] ^ (ks << 5)));
    if (t + 2 < NT) stage_half(Wb, bn, kc2, lds[cur][2], tid);
    BAR(); LGKM0(); PRIO(1);
#pragma unroll
    for (int ks = 0; ks < 2; ++ks)
#pragma unroll
      for (int mi = 0; mi < 2; ++mi)
#pragma unroll
        for (int ni = 0; ni < 2; ++ni)
          acc[2 + mi][ni] = MFMA32(a23[mi][ks], bb[ni][ks], acc[2 + mi][ni]);
    PRIO(0); BAR();

    // ---- P3: rd a0-1 + b0-1 (kh1); stage A-k0(t+2); 8 MFMA m0-1 ----
#pragma unroll
    for (int mi = 0; mi < 2; ++mi)
#pragma unroll
      for (int ks = 0; ks < 2; ++ks) a01[mi][ks] = RD(A1h + (aoff[mi] ^ (ks << 5)));
#pragma unroll
    for (int ni = 0; ni < 2; ++ni)
#pragma unroll
      for (int ks = 0; ks < 2; ++ks) bb[ni][ks] = RD(B1h + (boff[ni] ^ (ks << 5)));
    if (t + 2 < NT) stage_half(Xb, bm, kc2, lds[cur][0], tid);
    BAR(); LGKM0(); PRIO(1);
#pragma unroll
    for (int ks = 0; ks < 2; ++ks)
#pragma unroll
      for (int mi = 0; mi < 2; ++mi)
#pragma unroll
        for (int ni = 0; ni < 2; ++ni)
          acc[mi][ni] = MFMA32(a01[mi][ks], bb[ni][ks], acc[mi][ni]);
    PRIO(0); BAR();

    // ---- P4: rd a2-3 (kh1); stage B-k1(t+2); vmcnt(6); 8 MFMA m2-3 ----
#pragma unroll
    for (int mi = 0; mi < 2; ++mi)
#pragma unroll
      for (int ks = 0; ks < 2; ++ks) a23[mi][ks] = RD(A1h + (aoff[2 + mi] ^ (ks << 5)));
    if (t + 2 < NT) {
      stage_half(Wb, bn, kc2 + 32, lds[cur][3], tid);
      VM6();
    } else {
      VM0();
    }
    BAR(); LGKM0(); PRIO(1);
#pragma unroll
    for (int ks = 0; ks < 2; ++ks)
#pragma unroll
      for (int mi = 0; mi < 2; ++mi)
#pragma unroll
        for (int ni = 0; ni < 2; ++ni)
          acc[2 + mi][ni] = MFMA32(a23[mi][ks], bb[ni][ks], acc[2 + mi][ni]);
    PRIO(0); BAR();

    cur ^= 1;
  }

  // epilogue: 32x32 C/D layout col = l&31, row = (reg&3) + 8*(reg>>2) + 4*(l>>5)
  const int erow0 = bm + wm * 128 + 4 * (l >> 5);
  const int ecol  = bn + wn * 64 + (l & 31);
#pragma unroll
  for (int mi = 0; mi < 4; ++mi) {
#pragma unroll
    for (int ni = 0; ni < 2; ++ni) {
      float* cp = C + (size_t)(erow0 + mi * 32) * N + ecol + ni * 32;
#pragma unroll
      for (int r = 0; r < 16; ++r)
        cp[(size_t)((r & 3) + 8 * (r >> 2)) * N] = acc[mi][ni][r];
    }
  }
}

extern "C" void kernel_launch(void* const* d_in, const int* in_sizes, int n_in,
                              void* d_out, int out_size, void* d_ws, size_t ws_size,
                              hipStream_t stream) {
  const float* x = (const float*)d_in[0];   // [8192, 4096]
  const float* W = (const float*)d_in[1];   // [4096, 4096]
  const float* A = (const float*)d_in[2];   // [4096, 16]
  const float* B = (const float*)d_in[3];   // [16, 4096]
  float* out = (float*)d_out;               // [8192, 4096]

  ushort_t* xb = (ushort_t*)d_ws;                                    // 64 MB
  ushort_t* wb = (ushort_t*)((char*)d_ws + (size_t)8192 * 4096 * 2); // 32 MB

  cvt_x<<<16384, 256, 0, stream>>>(x, xb);
  dim3 gw(4, 4096);
  build_weff<<<gw, 256, 0, stream>>>(W, A, B, wb);
  gemm256<<<512, 512, 0, stream>>>(xb, wb, out);  // grid 32x16 tiles, XCD-chunked
}

// Round 9
// 352.798 us; speedup vs baseline: 1.0327x; 1.0327x over previous
//
#include <hip/hip_runtime.h>

typedef __attribute__((ext_vector_type(8))) short short8;
typedef __attribute__((ext_vector_type(16))) float f32x16;
typedef unsigned short ushort_t;

#define BAR()   __builtin_amdgcn_s_barrier()
#define LGKM0() asm volatile("s_waitcnt lgkmcnt(0)" ::: "memory")
#define VM6()   asm volatile("s_waitcnt vmcnt(6)" ::: "memory")
#define VM0()   asm volatile("s_waitcnt vmcnt(0)" ::: "memory")
#define PRIO(n) __builtin_amdgcn_s_setprio(n)
#define MFMA32(a_, b_, c_) __builtin_amdgcn_mfma_f32_32x32x16_bf16(a_, b_, c_, 0, 0, 0)

// ---------- helpers ----------
__device__ __forceinline__ unsigned short f2bf(float f) {
  unsigned u = __builtin_bit_cast(unsigned, f);
  u += 0x7FFFu + ((u >> 16) & 1u);   // round-to-nearest-even
  return (unsigned short)(u >> 16);
}

__device__ __forceinline__ void gl_lds16(const void* g, void* l) {
  __builtin_amdgcn_global_load_lds(
      (const __attribute__((address_space(1))) void*)g,
      (__attribute__((address_space(3))) void*)l, 16, 0, 0);
}

// ---------- kernel 1: x (f32) -> bf16 ----------
__global__ __launch_bounds__(256) void cvt_x(const float* __restrict__ x,
                                             ushort_t* __restrict__ xb) {
  size_t i = ((size_t)blockIdx.x * 256 + threadIdx.x) * 8;
  float4 v0 = *(const float4*)(x + i);
  float4 v1 = *(const float4*)(x + i + 4);
  union { ushort_t s[8]; uint4 v; } o;
  o.s[0] = f2bf(v0.x); o.s[1] = f2bf(v0.y); o.s[2] = f2bf(v0.z); o.s[3] = f2bf(v0.w);
  o.s[4] = f2bf(v1.x); o.s[5] = f2bf(v1.y); o.s[6] = f2bf(v1.z); o.s[7] = f2bf(v1.w);
  *(uint4*)(xb + i) = o.v;
}

// ---------- kernel 2: W_eff = W + A@B, stored bf16 ----------
__global__ __launch_bounds__(256) void build_weff(const float* __restrict__ W,
                                                  const float* __restrict__ A,
                                                  const float* __restrict__ B,
                                                  ushort_t* __restrict__ Weff) {
  const int K = 4096, R = 16;
  const int n = blockIdx.y;
  const int k = (blockIdx.x * 256 + threadIdx.x) * 4;
  float4 w = *(const float4*)(W + (size_t)n * K + k);
  float a0 = w.x, a1 = w.y, a2 = w.z, a3 = w.w;
#pragma unroll
  for (int r = 0; r < R; ++r) {
    float a = A[n * R + r];
    float4 b = *(const float4*)(B + (size_t)r * K + k);
    a0 += a * b.x; a1 += a * b.y; a2 += a * b.z; a3 += a * b.w;
  }
  union { ushort_t s[4]; uint2 v; } o;
  o.s[0] = f2bf(a0); o.s[1] = f2bf(a1); o.s[2] = f2bf(a2); o.s[3] = f2bf(a3);
  *(uint2*)(Weff + (size_t)n * K + k) = o.v;
}

// ---------- kernel 3: 256x256 8-phase bf16 GEMM, 32x32x16 MFMA, 2-bit swizzle ----
// Round-8 base (schedule == round-4's measured-good 8-phase), ONE change:
// SECOND swizzle bit. Empirical zero-conflict signature (round 4, measured 0):
// per half-wave, read bank-start = 16*(l&1) + 8*((l>>3)&1) + 4*((l>>4)&1)
// -> 8 distinct 16B slots x 4 lanes. Rounds 6/7/8 (all 2.517e7 conflicts,
// +4cy/read) covered only 4 slots (missing bit-4 variation). Fix: XOR row
// bits {3,4} into byte bits {5,4}:
//   phys(row, kb) = row*64 + (kb ^ ((row>>3)&1)<<5 ^ ((row>>4)&1)<<4)
// Pure XOR (no carries), involution; applied on pre-swizzled global SOURCE at
// stage (LDS dest linear, rule 21) and on read addr. Read bank-start now
// exactly reproduces round-4's formula for both half-waves, A and B frags,
// both ks slices (ks -> XOR bit 5, still clean under the swizzle).
// Fragments (validated by round-8 pass, absmax 8.0):
//   A/B: lane row/col = l&31, k-chunk byte = (l>>5)*16, ks slice = ^32.
//   C/D: col = l&31, row = (reg&3) + 8*(reg>>2) + 4*(l>>5).
// Phases per K-tile (identical to rounds 4/8):
//   P1: rd a0-1 + b0-1 (kh0, 8); stage A-k1(t+1)->cur^1;      8 MFMA m0-1
//   P2: rd a2-3 (kh0, 4);        stage B-k0(t+2)->cur;        8 MFMA m2-3
//   P3: rd a0-1 + b0-1 (kh1, 8); stage A-k0(t+2)->cur;        8 MFMA m0-1
//   P4: rd a2-3 (kh1, 4);        stage B-k1(t+2)->cur; vmcnt(6); 8 MFMA m2-3
// WAR + vmcnt ledgers unchanged (verified rounds 4/8).

__device__ __forceinline__ void stage_half(const ushort_t* __restrict__ G, int row0, int kc,
                                           ushort_t* half, int tid) {
#pragma unroll
  for (int r = 0; r < 2; ++r) {
    const int idx  = r * 512 + tid;
    const int lrow = idx >> 2;                                    // 0..255
    const int cb   = ((idx & 3) * 16) ^ (((lrow >> 3) & 1) << 5)
                                      ^ (((lrow >> 4) & 1) << 4); // pre-swizzled source col (bytes)
    const ushort_t* src = G + (size_t)(row0 + lrow) * 4096 + kc + (cb >> 1);
    char* dst = (char*)half + (size_t)(r * 512 + (tid & ~63)) * 16; // wave-uniform; HW adds lane*16
    gl_lds16(src, dst);
  }
}

__global__ __launch_bounds__(512) void gemm256(const ushort_t* __restrict__ Xb,
                                               const ushort_t* __restrict__ Wb,
                                               float* __restrict__ C) {
  const int N = 4096;
  const int NT = 4096 / 64;                 // 64 K-tiles
  __shared__ __align__(16) ushort_t lds[2][4][256 * 32];  // [buf][A-k0,A-k1,B-k0,B-k1]

  const int tid = threadIdx.x;
  const int l   = tid & 63;
  const int w   = tid >> 6;
  const int wm  = w >> 2;                   // 0..1
  const int wn  = w & 3;                    // 0..3

  // T1: bijective XCD chunking — 512 blocks = 8 chunks of 8x8 tiles (grid 32x16)
  const int bid = blockIdx.x;
  const int c = bid & 7, q = bid >> 3;
  const int tm = (c >> 1) * 8 + (q >> 3);   // 0..31
  const int tn = (c & 1) * 8 + (q & 7);     // 0..15
  const int bm = tm * 256, bn = tn * 256;

  // fragment byte offsets within a [256][32] half (2-bit swizzled read side).
  // row stride 64 B; lane row = l&31; k-chunk byte = (l>>5)*16; ks slice = ^32.
  // row bits {3,4} = (l>>3)&1, (l>>4)&1 (mi*32/ni*32/wm*128/wn*64 don't touch them).
  const int colb0 = ((l >> 5) * 16) ^ (((l >> 3) & 1) << 5) ^ (((l >> 4) & 1) << 4);
  int aoff[4], boff[2];
#pragma unroll
  for (int mi = 0; mi < 4; ++mi) aoff[mi] = (wm * 128 + mi * 32 + (l & 31)) * 64 + colb0;
#pragma unroll
  for (int ni = 0; ni < 2; ++ni) boff[ni] = (wn * 64 + ni * 32 + (l & 31)) * 64 + colb0;

  f32x16 acc[4][2];
#pragma unroll
  for (int i = 0; i < 4; ++i)
#pragma unroll
    for (int j = 0; j < 2; ++j) acc[i][j] = (f32x16)(0.0f);

  // prologue: tile0 all 4 halves + tile1 {B-k0,A-k0,B-k1}; vmcnt(6) -> tile0 landed
  stage_half(Wb, bn, 0,  lds[0][2], tid);
  stage_half(Xb, bm, 0,  lds[0][0], tid);
  stage_half(Wb, bn, 32, lds[0][3], tid);
  stage_half(Xb, bm, 32, lds[0][1], tid);
  stage_half(Wb, bn, 64, lds[1][2], tid);
  stage_half(Xb, bm, 64, lds[1][0], tid);
  stage_half(Wb, bn, 96, lds[1][3], tid);
  VM6();
  BAR();

  short8 a01[2][2], a23[2][2], bb[2][2];   // [m-or-n idx][ks]

#define RD(P_) (*(const short8*)(P_))

  int cur = 0;
  for (int t = 0; t < NT; ++t) {
    const char* A0h = (const char*)lds[cur][0];
    const char* A1h = (const char*)lds[cur][1];
    const char* B0h = (const char*)lds[cur][2];
    const char* B1h = (const char*)lds[cur][3];
    const int kc2 = (t + 2) * 64;

    // ---- P1: rd a0-1 + b0-1 (kh0); stage A-k1(t+1); 8 MFMA m0-1 ----
#pragma unroll
    for (int mi = 0; mi < 2; ++mi)
#pragma unroll
      for (int ks = 0; ks < 2; ++ks) a01[mi][ks] = RD(A0h + (aoff[mi] ^ (ks << 5)));
#pragma unroll
    for (int ni = 0; ni < 2; ++ni)
#pragma unroll
      for (int ks = 0; ks < 2; ++ks) bb[ni][ks] = RD(B0h + (boff[ni] ^ (ks << 5)));
    if (t + 1 < NT) stage_half(Xb, bm, (t + 1) * 64 + 32, lds[cur ^ 1][1], tid);
    BAR(); LGKM0(); PRIO(1);
#pragma unroll
    for (int ks = 0; ks < 2; ++ks)
#pragma unroll
      for (int mi = 0; mi < 2; ++mi)
#pragma unroll
        for (int ni = 0; ni < 2; ++ni)
          acc[mi][ni] = MFMA32(a01[mi][ks], bb[ni][ks], acc[mi][ni]);
    PRIO(0); BAR();

    // ---- P2: rd a2-3 (kh0); stage B-k0(t+2); 8 MFMA m2-3 ----
#pragma unroll
    for (int mi = 0; mi < 2; ++mi)
#pragma unroll
      for (int ks = 0; ks < 2; ++ks) a23[mi][ks] = RD(A0h + (aoff[2 + mi] ^ (ks << 5)));
    if (t + 2 < NT) stage_half(Wb, bn, kc2, lds[cur][2], tid);
    BAR(); LGKM0(); PRIO(1);
#pragma unroll
    for (int ks = 0; ks < 2; ++ks)
#pragma unroll
      for (int mi = 0; mi < 2; ++mi)
#pragma unroll
        for (int ni = 0; ni < 2; ++ni)
          acc[2 + mi][ni] = MFMA32(a23[mi][ks], bb[ni][ks], acc[2 + mi][ni]);
    PRIO(0); BAR();

    // ---- P3: rd a0-1 + b0-1 (kh1); stage A-k0(t+2); 8 MFMA m0-1 ----
#pragma unroll
    for (int mi = 0; mi < 2; ++mi)
#pragma unroll
      for (int ks = 0; ks < 2; ++ks) a01[mi][ks] = RD(A1h + (aoff[mi] ^ (ks << 5)));
#pragma unroll
    for (int ni = 0; ni < 2; ++ni)
#pragma unroll
      for (int ks = 0; ks < 2; ++ks) bb[ni][ks] = RD(B1h + (boff[ni] ^ (ks << 5)));
    if (t + 2 < NT) stage_half(Xb, bm, kc2, lds[cur][0], tid);
    BAR(); LGKM0(); PRIO(1);
#pragma unroll
    for (int ks = 0; ks < 2; ++ks)
#pragma unroll
      for (int mi = 0; mi < 2; ++mi)
#pragma unroll
        for (int ni = 0; ni < 2; ++ni)
          acc[mi][ni] = MFMA32(a01[mi][ks], bb[ni][ks], acc[mi][ni]);
    PRIO(0); BAR();

    // ---- P4: rd a2-3 (kh1); stage B-k1(t+2); vmcnt(6); 8 MFMA m2-3 ----
#pragma unroll
    for (int mi = 0; mi < 2; ++mi)
#pragma unroll
      for (int ks = 0; ks < 2; ++ks) a23[mi][ks] = RD(A1h + (aoff[2 + mi] ^ (ks << 5)));
    if (t + 2 < NT) {
      stage_half(Wb, bn, kc2 + 32, lds[cur][3], tid);
      VM6();
    } else {
      VM0();
    }
    BAR(); LGKM0(); PRIO(1);
#pragma unroll
    for (int ks = 0; ks < 2; ++ks)
#pragma unroll
      for (int mi = 0; mi < 2; ++mi)
#pragma unroll
        for (int ni = 0; ni < 2; ++ni)
          acc[2 + mi][ni] = MFMA32(a23[mi][ks], bb[ni][ks], acc[2 + mi][ni]);
    PRIO(0); BAR();

    cur ^= 1;
  }

  // epilogue: 32x32 C/D layout col = l&31, row = (reg&3) + 8*(reg>>2) + 4*(l>>5)
  const int erow0 = bm + wm * 128 + 4 * (l >> 5);
  const int ecol  = bn + wn * 64 + (l & 31);
#pragma unroll
  for (int mi = 0; mi < 4; ++mi) {
#pragma unroll
    for (int ni = 0; ni < 2; ++ni) {
      float* cp = C + (size_t)(erow0 + mi * 32) * N + ecol + ni * 32;
#pragma unroll
      for (int r = 0; r < 16; ++r)
        cp[(size_t)((r & 3) + 8 * (r >> 2)) * N] = acc[mi][ni][r];
    }
  }
}

extern "C" void kernel_launch(void* const* d_in, const int* in_sizes, int n_in,
                              void* d_out, int out_size, void* d_ws, size_t ws_size,
                              hipStream_t stream) {
  const float* x = (const float*)d_in[0];   // [8192, 4096]
  const float* W = (const float*)d_in[1];   // [4096, 4096]
  const float* A = (const float*)d_in[2];   // [4096, 16]
  const float* B = (const float*)d_in[3];   // [16, 4096]
  float* out = (float*)d_out;               // [8192, 4096]

  ushort_t* xb = (ushort_t*)d_ws;                                    // 64 MB
  ushort_t* wb = (ushort_t*)((char*)d_ws + (size_t)8192 * 4096 * 2); // 32 MB

  cvt_x<<<16384, 256, 0, stream>>>(x, xb);
  dim3 gw(4, 4096);
  build_weff<<<gw, 256, 0, stream>>>(W, A, B, wb);
  gemm256<<<512, 512, 0, stream>>>(xb, wb, out);  // grid 32x16 tiles, XCD-chunked
}